// Round 1
// baseline (295.873 us; speedup 1.0000x reference)
//
#include <hip/hip_runtime.h>

// DeepseekV3MoEToA2AAdapter: T=2048 tokens, H=1024, E=8, I=1408, top-2.
// fp32 I/O. LDS-transpose weight cast -> bf16 [E][N][K] (coalesced 128B
// write segments); atomic-free router; 512-thread (8-wave) MFMA GEMMs for
// occupancy; non-atomic split-K down + 4-way combine.
#define T_TOK 2048
#define HDIM  1024
#define NEXP  8
#define IDIM  1408

#define BM 128
#define BN 64
#define BK 32
#define KPAD 40     // bf16 elems; 80 B rows, 16B-aligned
#define MT_SLOTS 16
#define GU_NT 22    // IDIM / BN
#define DN_NT 16    // HDIM / BN
#define DK_HALF 704 // IDIM / 2 (split-K for down)

typedef __attribute__((ext_vector_type(8))) short bf16x8;
typedef __attribute__((ext_vector_type(4))) float f32x4;

static __device__ __forceinline__ unsigned short f2bf(float f) {
    union { float f; unsigned u; } a; a.f = f;
    return (unsigned short)((a.u + 0x7fffu + ((a.u >> 16) & 1u)) >> 16);
}

// ------------------------------------------- router pass 1: compute ---------
// One wave per token; fp64 ladder (robust top-2 ordering); fused x->bf16.
// NO device-scope atomics: writes sel[t] = e1 | (e2<<8) and w1[t].
__global__ __launch_bounds__(256) void router_compute_kernel(
    const float* __restrict__ x,        // [T, H]
    const float* __restrict__ rw,       // [H, E]
    int*   __restrict__ sel,            // [T]
    float* __restrict__ w1arr,          // [T]
    unsigned short* __restrict__ xb)    // [T, H] bf16
{
    __shared__ float rwT[NEXP][HDIM];   // 32 KB
    const int tid = threadIdx.x;
#pragma unroll
    for (int p = 0; p < 4; ++p) {
        const int h = tid + 256 * p;
        const float4 a = *(const float4*)(rw + (size_t)h * 8);
        const float4 b = *(const float4*)(rw + (size_t)h * 8 + 4);
        rwT[0][h] = a.x; rwT[1][h] = a.y; rwT[2][h] = a.z; rwT[3][h] = a.w;
        rwT[4][h] = b.x; rwT[5][h] = b.y; rwT[6][h] = b.z; rwT[7][h] = b.w;
    }
    __syncthreads();

    const int wave = (blockIdx.x * blockDim.x + threadIdx.x) >> 6;
    const int lane = threadIdx.x & 63;
    if (wave >= T_TOK) return;
    const int t = wave;

    float xr[16];
    const float* xp = x + (size_t)t * HDIM;
#pragma unroll
    for (int i = 0; i < 16; ++i) xr[i] = xp[lane + 64 * i];

    unsigned short* xbp = xb + (size_t)t * HDIM;
#pragma unroll
    for (int i = 0; i < 16; ++i) xbp[lane + 64 * i] = f2bf(xr[i]);

    double logits[NEXP];
#pragma unroll
    for (int e = 0; e < NEXP; ++e) {
        double s = 0.0;
#pragma unroll
        for (int i = 0; i < 16; ++i)
            s += (double)xr[i] * (double)rwT[e][lane + 64 * i];
#pragma unroll
        for (int off = 32; off > 0; off >>= 1)
            s += __shfl_down(s, off, 64);
        logits[e] = s;
    }

    if (lane == 0) {
        int e1 = 0;
        for (int e = 1; e < NEXP; ++e) if (logits[e] > logits[e1]) e1 = e;
        int e2 = -1;
        for (int e = 0; e < NEXP; ++e) {
            if (e == e1) continue;
            if (e2 < 0 || logits[e] > logits[e2]) e2 = e;
        }
        const double w1 = 1.0 / (1.0 + exp(logits[e2] - logits[e1]));
        sel[t]   = e1 | (e2 << 8);
        w1arr[t] = (float)w1;
    }
}

// ------------------------------------------- router pass 2: scatter ---------
// ONE block, 1024 threads. All fetch-adds are LDS-scope (single CU) -> no
// cross-XCD fabric serialization. List order within an expert is irrelevant.
__global__ __launch_bounds__(1024) void router_scatter_kernel(
    const int* __restrict__ sel, const float* __restrict__ w1arr,
    int* __restrict__ counts,
    int* __restrict__ tok_list, float* __restrict__ wgt_list,
    int* __restrict__ row_list)
{
    __shared__ int cnt[NEXP];
    const int tid = threadIdx.x;
    if (tid < NEXP) cnt[tid] = 0;
    __syncthreads();
    for (int t = tid; t < T_TOK; t += 1024) {
        const int s  = sel[t];
        const int e1 = s & 255, e2 = s >> 8;
        const float w1 = w1arr[t];
        const int p1 = atomicAdd(&cnt[e1], 1);
        tok_list[e1 * T_TOK + p1] = t;
        wgt_list[e1 * T_TOK + p1] = w1;
        row_list[e1 * T_TOK + p1] = 2 * t;
        const int p2 = atomicAdd(&cnt[e2], 1);
        tok_list[e2 * T_TOK + p2] = t;
        wgt_list[e2 * T_TOK + p2] = 1.0f - w1;
        row_list[e2 * T_TOK + p2] = 2 * t + 1;
    }
    __syncthreads();
    if (tid < NEXP) counts[tid] = cnt[tid];
}

// ---------------------- weight cast+transpose via LDS (coalesced writes) ----
// fp32 [E][K][N] -> bf16 [E][N][K]. Per block: 64k x 128n tile.
// Read: float4/lane, contiguous-n (256 B segments, as before).
// Transpose through LDS [128n][64k+2pad] (132 B rows: scattered b16 writes
// land on distinct-bank phases). Write-out: 16 B/lane, 8 lanes per n-row =
// 128 B fully-coalesced segments (old path: 64x 8 B scatter at 8 KB stride).
__global__ __launch_bounds__(256) void wtrans_all_kernel(
    const float* __restrict__ gw, const float* __restrict__ uw,
    const float* __restrict__ dw,
    unsigned short* __restrict__ gwt, unsigned short* __restrict__ uwt,
    unsigned short* __restrict__ dwt)
{
    const int z  = blockIdx.z;
    const int bx = blockIdx.x;          // 0..175
    const float* src; unsigned short* dst; int K, N, kb, nb;
    if (z < 16) {
        K = HDIM; N = IDIM;
        const int e = z & 7;
        src = (z < 8 ? gw : uw) + (size_t)e * K * N;
        dst = (z < 8 ? gwt : uwt) + (size_t)e * (size_t)N * K;
        nb = bx % 11; kb = bx / 11;     // 11 n-tiles x 16 k-tiles
    } else {
        K = IDIM; N = HDIM;
        const int e = z - 16;
        src = dw + (size_t)e * K * N;
        dst = dwt + (size_t)e * (size_t)N * K;
        nb = bx & 7; kb = bx >> 3;      // 8 n-tiles x 22 k-tiles
    }
    const int k0 = kb * 64;
    const int n0 = nb * 128;

    __shared__ unsigned short tb[128][66];   // [n][k], +2 pad -> 132 B rows

    const int tid = threadIdx.x;
    const int lk = tid >> 5;            // 0..7 (k sub-row)
    const int ln = (tid & 31) * 4;      // 0..124 (n)
#pragma unroll
    for (int r = 0; r < 8; ++r) {
        const int k = r * 8 + lk;
        const float4 v = *(const float4*)(src + (size_t)(k0 + k) * N + n0 + ln);
        tb[ln + 0][k] = f2bf(v.x);
        tb[ln + 1][k] = f2bf(v.y);
        tb[ln + 2][k] = f2bf(v.z);
        tb[ln + 3][k] = f2bf(v.w);
    }
    __syncthreads();

    const int wn = tid >> 3;            // 0..31 (n sub-row)
    const int wk = (tid & 7) * 8;       // 0..56 (k chunk)
#pragma unroll
    for (int p = 0; p < 4; ++p) {
        const int n = p * 32 + wn;
        const unsigned* rp = (const unsigned*)&tb[n][wk];  // 4 B aligned
        uint4 o;
        o.x = rp[0]; o.y = rp[1]; o.z = rp[2]; o.w = rp[3];
        *(uint4*)(dst + (size_t)(n0 + n) * K + k0 + wk) = o;
    }
}

// -------------------------------------------------- fused gate+up GEMM -----
// 512 threads / 8 waves (32x32 wave tiles): ~704 active blocks were only
// 2.75 waves/SIMD at 256 threads (Occupancy 24%); this doubles resident
// waves without changing global traffic or the verified MFMA index math.
__global__ __launch_bounds__(512, 4) void gateup_kernel(
    const unsigned short* __restrict__ xb,    // [T,H] bf16
    const unsigned short* __restrict__ gwt,   // [E][I][H] bf16
    const unsigned short* __restrict__ uwt,   // [E][I][H] bf16
    const float* __restrict__ gb, const float* __restrict__ ub,
    const int* __restrict__ counts,
    const int* __restrict__ tok_list,
    const int* __restrict__ row_list,
    unsigned short* __restrict__ act)         // [2T, IDIM] bf16
{
    const int flat = blockIdx.x;
    const int xcd  = flat & 7;
    const int q    = flat >> 3;
    const int mt   = q & 15;
    const int slot = q >> 4;
    const int P    = slot * 8 + xcd;   // 0..175 = (e, nt), fixed XCD per (e,nt)
    const int e    = P / GU_NT;
    const int nt   = P % GU_NT;
    const int n_e  = counts[e];
    const int m0   = mt * BM;
    if (m0 >= n_e) return;
    const int n0 = nt * BN;

    const unsigned short* gwp = gwt + (size_t)e * IDIM * HDIM;
    const unsigned short* uwp = uwt + (size_t)e * IDIM * HDIM;
    const float* gbp = gb + (size_t)e * IDIM;
    const float* ubp = ub + (size_t)e * IDIM;

    __shared__ unsigned short As[BM][KPAD];
    __shared__ unsigned short Bg[BN][KPAD];
    __shared__ unsigned short Bu[BN][KPAD];
    __shared__ int gr_lds[BM];
    __shared__ int or_lds[BM];

    const int tid = threadIdx.x;
    const int base = e * T_TOK;
    if (tid < BM) {
        const int m = m0 + tid;
        int g = -1, o = -1;
        if (m < n_e) { g = tok_list[base + m]; o = row_list[base + m]; }
        gr_lds[tid] = g; or_lds[tid] = o;
    }
    __syncthreads();

    // A staging: 128 rows x 4 chunks of 8 bf16 = 512 chunks = 512 threads
    const int ar = tid >> 2;
    const int ac = (tid & 3) * 8;
    const int arow = gr_lds[ar];
    const unsigned short* ap = xb + (size_t)(arow < 0 ? 0 : arow) * HDIM + ac;
    unsigned short* Adst = &As[0][0] + ar * KPAD + ac;
    // B staging: tid<256 -> gate, tid>=256 -> up (64 rows x 4 chunks each)
    const int u    = tid & 255;
    const int brow = u >> 2;
    const int bch  = (u & 3) * 8;
    const unsigned short* bsrc =
        ((tid >> 8) ? uwp : gwp) + (size_t)(n0 + brow) * HDIM + bch;
    unsigned short* Bdst =
        ((tid >> 8) ? &Bu[0][0] : &Bg[0][0]) + brow * KPAD + bch;

    const int wv = tid >> 6, lane = tid & 63;
    const int wm = (wv & 3) * 32, wn = (wv >> 2) * 32;
    const int l16 = lane & 15, quad = lane >> 4;

    f32x4 accg[2][2], accu[2][2];
    const f32x4 zero = {0.0f, 0.0f, 0.0f, 0.0f};
#pragma unroll
    for (int i = 0; i < 2; ++i)
#pragma unroll
        for (int j = 0; j < 2; ++j) { accg[i][j] = zero; accu[i][j] = zero; }

    uint4 PA = {0, 0, 0, 0}, PB;
    if (arow >= 0) PA = *(const uint4*)(ap);
    PB = *(const uint4*)(bsrc);

    for (int k0 = 0; k0 < HDIM; k0 += BK) {
        __syncthreads();
        *(uint4*)Adst = PA;
        *(uint4*)Bdst = PB;
        __syncthreads();

        const int kn = k0 + BK;
        if (kn < HDIM) {
            if (arow >= 0) PA = *(const uint4*)(ap + kn);
            PB = *(const uint4*)(bsrc + kn);
        }

        bf16x8 af[2], bgf[2], buf_[2];
#pragma unroll
        for (int i = 0; i < 2; ++i)
            af[i] = *(const bf16x8*)&As[wm + i * 16 + l16][quad * 8];
#pragma unroll
        for (int j = 0; j < 2; ++j) {
            bgf[j]  = *(const bf16x8*)&Bg[wn + j * 16 + l16][quad * 8];
            buf_[j] = *(const bf16x8*)&Bu[wn + j * 16 + l16][quad * 8];
        }
#pragma unroll
        for (int i = 0; i < 2; ++i)
#pragma unroll
            for (int j = 0; j < 2; ++j) {
                accg[i][j] = __builtin_amdgcn_mfma_f32_16x16x32_bf16(
                    af[i], bgf[j], accg[i][j], 0, 0, 0);
                accu[i][j] = __builtin_amdgcn_mfma_f32_16x16x32_bf16(
                    af[i], buf_[j], accu[i][j], 0, 0, 0);
            }
    }

    // epilogue: silu(g)*u -> bf16 act
#pragma unroll
    for (int j = 0; j < 2; ++j) {
        const int nl = n0 + wn + j * 16 + l16;
        const float gbv = gbp[nl];
        const float ubv = ubp[nl];
#pragma unroll
        for (int i = 0; i < 2; ++i) {
#pragma unroll
            for (int ii = 0; ii < 4; ++ii) {
                const int ml = wm + i * 16 + quad * 4 + ii;
                const int orow = or_lds[ml];
                if (orow >= 0) {
                    const float g = accg[i][j][ii] + gbv;
                    const float uu = accu[i][j][ii] + ubv;
                    act[(size_t)orow * IDIM + nl] =
                        f2bf(g * uu / (1.0f + __expf(-g)));
                }
            }
        }
    }
}

// ------------------------------------------------------- down-proj GEMM ----
// Split-K=2, NON-ATOMIC: slice sk writes plain stores into y2 + sk*(2T*H).
// 512 threads / 8 waves for occupancy (same rationale as gateup).
__global__ __launch_bounds__(512, 4) void down_kernel(
    const unsigned short* __restrict__ act,   // [2T, IDIM] bf16
    const unsigned short* __restrict__ dwt,   // [E][H][I] bf16
    const float* __restrict__ db,
    const int* __restrict__ counts,
    const float* __restrict__ wgt_list,
    const int* __restrict__ row_list,
    float* __restrict__ y2)                   // [2][2T, HDIM] fp32
{
    const int flat = blockIdx.x;
    const int xcd  = flat & 7;
    const int q    = flat >> 3;
    const int mt   = q & 15;
    const int slot = q >> 4;
    const int P    = slot * 8 + xcd;   // 0..255 = (sk, e, nt)
    const int sk   = P & 1;
    const int en   = P >> 1;
    const int e    = en >> 4;
    const int nt   = en & 15;
    const int n_e  = counts[e];
    const int m0   = mt * BM;
    if (m0 >= n_e) return;
    const int n0 = nt * BN;
    const int ks = sk * DK_HALF;
    float* y2s = y2 + (size_t)sk * 2 * T_TOK * HDIM;

    const unsigned short* dwp = dwt + (size_t)e * HDIM * IDIM;
    const float* dbp = db + (size_t)e * HDIM;

    __shared__ unsigned short As[BM][KPAD];
    __shared__ unsigned short Bs[BN][KPAD];
    __shared__ int   r_lds[BM];
    __shared__ float w_lds[BM];

    const int tid = threadIdx.x;
    const int base = e * T_TOK;
    if (tid < BM) {
        const int m = m0 + tid;
        int r = -1; float w = 0.0f;
        if (m < n_e) { r = row_list[base + m]; w = wgt_list[base + m]; }
        r_lds[tid] = r; w_lds[tid] = w;
    }
    __syncthreads();

    const int ar = tid >> 2;
    const int ac = (tid & 3) * 8;
    const int arow = r_lds[ar];
    const unsigned short* ap =
        act + (size_t)(arow < 0 ? 0 : arow) * IDIM + ks + ac;
    unsigned short* Adst = &As[0][0] + ar * KPAD + ac;
    const bool hasB = tid < 256;
    const int brow = (tid & 255) >> 2;
    const int bch  = (tid & 3) * 8;
    const unsigned short* bsrc = dwp + (size_t)(n0 + brow) * IDIM + ks + bch;
    unsigned short* Bdst = &Bs[0][0] + brow * KPAD + bch;

    const int wv = tid >> 6, lane = tid & 63;
    const int wm = (wv & 3) * 32, wn = (wv >> 2) * 32;
    const int l16 = lane & 15, quad = lane >> 4;

    f32x4 acc[2][2];
    const f32x4 zero = {0.0f, 0.0f, 0.0f, 0.0f};
#pragma unroll
    for (int i = 0; i < 2; ++i)
#pragma unroll
        for (int j = 0; j < 2; ++j) acc[i][j] = zero;

    uint4 PA = {0, 0, 0, 0}, PB = {0, 0, 0, 0};
    if (arow >= 0) PA = *(const uint4*)(ap);
    if (hasB) PB = *(const uint4*)(bsrc);

    for (int k0 = 0; k0 < DK_HALF; k0 += BK) {
        __syncthreads();
        *(uint4*)Adst = PA;
        if (hasB) *(uint4*)Bdst = PB;
        __syncthreads();

        const int kn = k0 + BK;
        if (kn < DK_HALF) {
            if (arow >= 0) PA = *(const uint4*)(ap + kn);
            if (hasB) PB = *(const uint4*)(bsrc + kn);
        }

        bf16x8 af[2], bfr[2];
#pragma unroll
        for (int i = 0; i < 2; ++i)
            af[i] = *(const bf16x8*)&As[wm + i * 16 + l16][quad * 8];
#pragma unroll
        for (int j = 0; j < 2; ++j)
            bfr[j] = *(const bf16x8*)&Bs[wn + j * 16 + l16][quad * 8];
#pragma unroll
        for (int i = 0; i < 2; ++i)
#pragma unroll
            for (int j = 0; j < 2; ++j)
                acc[i][j] = __builtin_amdgcn_mfma_f32_16x16x32_bf16(
                    af[i], bfr[j], acc[i][j], 0, 0, 0);
    }

#pragma unroll
    for (int j = 0; j < 2; ++j) {
        const int nl = n0 + wn + j * 16 + l16;
        const float bv = (sk == 0) ? dbp[nl] : 0.0f;
#pragma unroll
        for (int i = 0; i < 2; ++i) {
#pragma unroll
            for (int ii = 0; ii < 4; ++ii) {
                const int ml = wm + i * 16 + quad * 4 + ii;
                const int rr = r_lds[ml];
                if (rr >= 0)
                    y2s[(size_t)rr * HDIM + nl] = w_lds[ml] * (acc[i][j][ii] + bv);
            }
        }
    }
}

// --------------------------------------------------------------- combine ----
__global__ __launch_bounds__(256) void combine_kernel(
    const float* __restrict__ y2, float* __restrict__ out)
{
    const int idx = (blockIdx.x * 256 + threadIdx.x) * 4;   // < T*H
    const int t = idx >> 10;           // HDIM == 1024
    const int h = idx & 1023;
    const float* y2b = y2 + (size_t)2 * T_TOK * HDIM;
    const float4 a0 = *(const float4*)(y2  + ((size_t)2 * t) * HDIM + h);
    const float4 a1 = *(const float4*)(y2  + ((size_t)2 * t + 1) * HDIM + h);
    const float4 b0 = *(const float4*)(y2b + ((size_t)2 * t) * HDIM + h);
    const float4 b1 = *(const float4*)(y2b + ((size_t)2 * t + 1) * HDIM + h);
    float4 o;
    o.x = a0.x + a1.x + b0.x + b1.x;
    o.y = a0.y + a1.y + b0.y + b1.y;
    o.z = a0.z + a1.z + b0.z + b1.z;
    o.w = a0.w + a1.w + b0.w + b1.w;
    *(float4*)(out + idx) = o;
}

// ---------------------------------------------------------------- launch ----
extern "C" void kernel_launch(void* const* d_in, const int* in_sizes, int n_in,
                              void* d_out, int out_size, void* d_ws, size_t ws_size,
                              hipStream_t stream)
{
    const float* x      = (const float*)d_in[0];
    const float* rw     = (const float*)d_in[1];
    const float* gate_w = (const float*)d_in[2];
    const float* up_w   = (const float*)d_in[3];
    const float* down_w = (const float*)d_in[4];
    const float* gate_b = (const float*)d_in[5];
    const float* up_b   = (const float*)d_in[6];
    const float* down_b = (const float*)d_in[7];
    float* out = (float*)d_out;

    // workspace layout (~85 MB; y2[2 slices, 32 MB] aliases gwt+uwt,
    // which are dead after gateup)
    char* ws = (char*)d_ws;
    size_t off = 0;
    int*   counts   = (int*)(ws + off);  off += 256;
    int*   tok_list = (int*)(ws + off);  off += 65536;
    float* wgt_list = (float*)(ws + off); off += 65536;
    int*   row_list = (int*)(ws + off);  off += 65536;
    int*   sel      = (int*)(ws + off);  off += T_TOK * 4;
    float* w1arr    = (float*)(ws + off); off += T_TOK * 4;
    unsigned short* x_bf = (unsigned short*)(ws + off); off += (size_t)T_TOK * HDIM * 2;       // 4 MB
    unsigned short* act  = (unsigned short*)(ws + off); off += (size_t)2 * T_TOK * IDIM * 2;   // 11.5 MB
    unsigned short* dwt  = (unsigned short*)(ws + off); off += (size_t)NEXP * IDIM * HDIM * 2; // 23 MB
    unsigned short* gwt  = (unsigned short*)(ws + off); off += (size_t)NEXP * IDIM * HDIM * 2; // 23 MB
    unsigned short* uwt  = (unsigned short*)(ws + off);                                        // 23 MB
    float* y2 = (float*)gwt;   // 2 x 16 MB slices, reused after gateup

    wtrans_all_kernel<<<dim3(176, 1, 24), 256, 0, stream>>>(
        gate_w, up_w, down_w, gwt, uwt, dwt);

    router_compute_kernel<<<T_TOK / 4, 256, 0, stream>>>(x, rw, sel, w1arr, x_bf);

    router_scatter_kernel<<<1, 1024, 0, stream>>>(
        sel, w1arr, counts, tok_list, wgt_list, row_list);

    gateup_kernel<<<8 * GU_NT * MT_SLOTS, 512, 0, stream>>>(
        x_bf, gwt, uwt, gate_b, up_b, counts, tok_list, row_list, act);

    down_kernel<<<2 * 8 * DN_NT * MT_SLOTS, 512, 0, stream>>>(
        act, dwt, down_b, counts, wgt_list, row_list, y2);

    combine_kernel<<<(T_TOK * HDIM / 4) / 256, 256, 0, stream>>>(y2, out);
}

// Round 2
// 294.891 us; speedup vs baseline: 1.0033x; 1.0033x over previous
//
#include <hip/hip_runtime.h>

// DeepseekV3MoEToA2AAdapter: T=2048 tokens, H=1024, E=8, I=1408, top-2.
// fp32 I/O. LDS-transpose weight cast -> bf16 [E][N][K]; atomic-free router;
// 256-thread 4-wave MFMA GEMMs with BK=64 (half the barrier drains of BK=32,
// 8 uint4 prefetch loads in flight per thread); non-atomic split-K down +
// 4-way combine.
#define T_TOK 2048
#define HDIM  1024
#define NEXP  8
#define IDIM  1408

#define BM 128
#define BN 64
#define BK 64
#define KPAD 72     // bf16 elems; 144 B rows -> 36 words % 32 = 4: 2-way (free)
#define MT_SLOTS 16
#define GU_NT 22    // IDIM / BN
#define DN_NT 16    // HDIM / BN
#define DK_HALF 704 // IDIM / 2 (split-K for down); 11 BK=64 steps

typedef __attribute__((ext_vector_type(8))) short bf16x8;
typedef __attribute__((ext_vector_type(4))) float f32x4;

static __device__ __forceinline__ unsigned short f2bf(float f) {
    union { float f; unsigned u; } a; a.f = f;
    return (unsigned short)((a.u + 0x7fffu + ((a.u >> 16) & 1u)) >> 16);
}

// ------------------------------------------- router pass 1: compute ---------
// One wave per token; fp64 ladder (robust top-2 ordering); fused x->bf16.
__global__ __launch_bounds__(256) void router_compute_kernel(
    const float* __restrict__ x,        // [T, H]
    const float* __restrict__ rw,       // [H, E]
    int*   __restrict__ sel,            // [T]
    float* __restrict__ w1arr,          // [T]
    unsigned short* __restrict__ xb)    // [T, H] bf16
{
    __shared__ float rwT[NEXP][HDIM];   // 32 KB
    const int tid = threadIdx.x;
#pragma unroll
    for (int p = 0; p < 4; ++p) {
        const int h = tid + 256 * p;
        const float4 a = *(const float4*)(rw + (size_t)h * 8);
        const float4 b = *(const float4*)(rw + (size_t)h * 8 + 4);
        rwT[0][h] = a.x; rwT[1][h] = a.y; rwT[2][h] = a.z; rwT[3][h] = a.w;
        rwT[4][h] = b.x; rwT[5][h] = b.y; rwT[6][h] = b.z; rwT[7][h] = b.w;
    }
    __syncthreads();

    const int wave = (blockIdx.x * blockDim.x + threadIdx.x) >> 6;
    const int lane = threadIdx.x & 63;
    if (wave >= T_TOK) return;
    const int t = wave;

    float xr[16];
    const float* xp = x + (size_t)t * HDIM;
#pragma unroll
    for (int i = 0; i < 16; ++i) xr[i] = xp[lane + 64 * i];

    unsigned short* xbp = xb + (size_t)t * HDIM;
#pragma unroll
    for (int i = 0; i < 16; ++i) xbp[lane + 64 * i] = f2bf(xr[i]);

    double logits[NEXP];
#pragma unroll
    for (int e = 0; e < NEXP; ++e) {
        double s = 0.0;
#pragma unroll
        for (int i = 0; i < 16; ++i)
            s += (double)xr[i] * (double)rwT[e][lane + 64 * i];
#pragma unroll
        for (int off = 32; off > 0; off >>= 1)
            s += __shfl_down(s, off, 64);
        logits[e] = s;
    }

    if (lane == 0) {
        int e1 = 0;
        for (int e = 1; e < NEXP; ++e) if (logits[e] > logits[e1]) e1 = e;
        int e2 = -1;
        for (int e = 0; e < NEXP; ++e) {
            if (e == e1) continue;
            if (e2 < 0 || logits[e] > logits[e2]) e2 = e;
        }
        const double w1 = 1.0 / (1.0 + exp(logits[e2] - logits[e1]));
        sel[t]   = e1 | (e2 << 8);
        w1arr[t] = (float)w1;
    }
}

// ------------------------------------------- router pass 2: scatter ---------
__global__ __launch_bounds__(1024) void router_scatter_kernel(
    const int* __restrict__ sel, const float* __restrict__ w1arr,
    int* __restrict__ counts,
    int* __restrict__ tok_list, float* __restrict__ wgt_list,
    int* __restrict__ row_list)
{
    __shared__ int cnt[NEXP];
    const int tid = threadIdx.x;
    if (tid < NEXP) cnt[tid] = 0;
    __syncthreads();
    for (int t = tid; t < T_TOK; t += 1024) {
        const int s  = sel[t];
        const int e1 = s & 255, e2 = s >> 8;
        const float w1 = w1arr[t];
        const int p1 = atomicAdd(&cnt[e1], 1);
        tok_list[e1 * T_TOK + p1] = t;
        wgt_list[e1 * T_TOK + p1] = w1;
        row_list[e1 * T_TOK + p1] = 2 * t;
        const int p2 = atomicAdd(&cnt[e2], 1);
        tok_list[e2 * T_TOK + p2] = t;
        wgt_list[e2 * T_TOK + p2] = 1.0f - w1;
        row_list[e2 * T_TOK + p2] = 2 * t + 1;
    }
    __syncthreads();
    if (tid < NEXP) counts[tid] = cnt[tid];
}

// ---------------------- weight cast+transpose via LDS (coalesced writes) ----
__global__ __launch_bounds__(256) void wtrans_all_kernel(
    const float* __restrict__ gw, const float* __restrict__ uw,
    const float* __restrict__ dw,
    unsigned short* __restrict__ gwt, unsigned short* __restrict__ uwt,
    unsigned short* __restrict__ dwt)
{
    const int z  = blockIdx.z;
    const int bx = blockIdx.x;          // 0..175
    const float* src; unsigned short* dst; int K, N, kb, nb;
    if (z < 16) {
        K = HDIM; N = IDIM;
        const int e = z & 7;
        src = (z < 8 ? gw : uw) + (size_t)e * K * N;
        dst = (z < 8 ? gwt : uwt) + (size_t)e * (size_t)N * K;
        nb = bx % 11; kb = bx / 11;     // 11 n-tiles x 16 k-tiles
    } else {
        K = IDIM; N = HDIM;
        const int e = z - 16;
        src = dw + (size_t)e * K * N;
        dst = dwt + (size_t)e * (size_t)N * K;
        nb = bx & 7; kb = bx >> 3;      // 8 n-tiles x 22 k-tiles
    }
    const int k0 = kb * 64;
    const int n0 = nb * 128;

    __shared__ unsigned short tb[128][66];   // [n][k], +2 pad -> 132 B rows

    const int tid = threadIdx.x;
    const int lk = tid >> 5;            // 0..7 (k sub-row)
    const int ln = (tid & 31) * 4;      // 0..124 (n)
#pragma unroll
    for (int r = 0; r < 8; ++r) {
        const int k = r * 8 + lk;
        const float4 v = *(const float4*)(src + (size_t)(k0 + k) * N + n0 + ln);
        tb[ln + 0][k] = f2bf(v.x);
        tb[ln + 1][k] = f2bf(v.y);
        tb[ln + 2][k] = f2bf(v.z);
        tb[ln + 3][k] = f2bf(v.w);
    }
    __syncthreads();

    const int wn = tid >> 3;            // 0..31 (n sub-row)
    const int wk = (tid & 7) * 8;       // 0..56 (k chunk)
#pragma unroll
    for (int p = 0; p < 4; ++p) {
        const int n = p * 32 + wn;
        const unsigned* rp = (const unsigned*)&tb[n][wk];  // 4 B aligned
        uint4 o;
        o.x = rp[0]; o.y = rp[1]; o.z = rp[2]; o.w = rp[3];
        *(uint4*)(dst + (size_t)(n0 + n) * K + k0 + wk) = o;
    }
}

// -------------------------------------------------- fused gate+up GEMM -----
// 256 threads / 4 waves (proven layout); BK=64: 32 MFMAs per barrier pair,
// 8 uint4 prefetch loads in flight per thread. LDS ~37 KB (<= grid-limited
// occupancy of ~2.75 blocks/CU, so no occupancy cost).
__global__ __launch_bounds__(256) void gateup_kernel(
    const unsigned short* __restrict__ xb,    // [T,H] bf16
    const unsigned short* __restrict__ gwt,   // [E][I][H] bf16
    const unsigned short* __restrict__ uwt,   // [E][I][H] bf16
    const float* __restrict__ gb, const float* __restrict__ ub,
    const int* __restrict__ counts,
    const int* __restrict__ tok_list,
    const int* __restrict__ row_list,
    unsigned short* __restrict__ act)         // [2T, IDIM] bf16
{
    const int flat = blockIdx.x;
    const int xcd  = flat & 7;
    const int q    = flat >> 3;
    const int mt   = q & 15;
    const int slot = q >> 4;
    const int P    = slot * 8 + xcd;   // 0..175 = (e, nt), fixed XCD per (e,nt)
    const int e    = P / GU_NT;
    const int nt   = P % GU_NT;
    const int n_e  = counts[e];
    const int m0   = mt * BM;
    if (m0 >= n_e) return;
    const int n0 = nt * BN;

    const unsigned short* gwp = gwt + (size_t)e * IDIM * HDIM;
    const unsigned short* uwp = uwt + (size_t)e * IDIM * HDIM;
    const float* gbp = gb + (size_t)e * IDIM;
    const float* ubp = ub + (size_t)e * IDIM;

    __shared__ unsigned short As[BM][KPAD];   // 18 KB
    __shared__ unsigned short Bg[BN][KPAD];   //  9 KB
    __shared__ unsigned short Bu[BN][KPAD];   //  9 KB
    __shared__ int gr_lds[BM];
    __shared__ int or_lds[BM];

    const int tid = threadIdx.x;
    const int base = e * T_TOK;
    if (tid < BM) {
        const int m = m0 + tid;
        int g = -1, o = -1;
        if (m < n_e) { g = tok_list[base + m]; o = row_list[base + m]; }
        gr_lds[tid] = g; or_lds[tid] = o;
    }
    __syncthreads();

    // A staging: 128 rows x 2 half-rows of 32 bf16 (64 B) = 256 threads
    const int ar = tid >> 1;
    const int ac = (tid & 1) * 32;
    const int arow = gr_lds[ar];
    const unsigned short* ap = xb + (size_t)(arow < 0 ? 0 : arow) * HDIM + ac;
    unsigned short* Adst = &As[0][0] + ar * KPAD + ac;
    // B staging: tid<128 -> gate, else up; 64 rows x 2 half-rows of 32
    const int u    = tid & 127;
    const int brow = u >> 1;
    const int bch  = (u & 1) * 32;
    const unsigned short* bsrc =
        ((tid >> 7) ? uwp : gwp) + (size_t)(n0 + brow) * HDIM + bch;
    unsigned short* Bdst =
        ((tid >> 7) ? &Bu[0][0] : &Bg[0][0]) + brow * KPAD + bch;

    const int wv = tid >> 6, lane = tid & 63;
    const int wm = (wv & 1) * 64, wn = (wv >> 1) * 32;
    const int l16 = lane & 15, quad = lane >> 4;

    f32x4 accg[4][2], accu[4][2];
    const f32x4 zero = {0.0f, 0.0f, 0.0f, 0.0f};
#pragma unroll
    for (int i = 0; i < 4; ++i)
#pragma unroll
        for (int j = 0; j < 2; ++j) { accg[i][j] = zero; accu[i][j] = zero; }

    uint4 PA0 = {0,0,0,0}, PA1 = {0,0,0,0}, PA2 = {0,0,0,0}, PA3 = {0,0,0,0};
    uint4 PB0, PB1, PB2, PB3;
    if (arow >= 0) {
        PA0 = *(const uint4*)(ap);
        PA1 = *(const uint4*)(ap + 8);
        PA2 = *(const uint4*)(ap + 16);
        PA3 = *(const uint4*)(ap + 24);
    }
    PB0 = *(const uint4*)(bsrc);
    PB1 = *(const uint4*)(bsrc + 8);
    PB2 = *(const uint4*)(bsrc + 16);
    PB3 = *(const uint4*)(bsrc + 24);

    for (int k0 = 0; k0 < HDIM; k0 += BK) {
        __syncthreads();
        *(uint4*)(Adst)      = PA0;
        *(uint4*)(Adst + 8)  = PA1;
        *(uint4*)(Adst + 16) = PA2;
        *(uint4*)(Adst + 24) = PA3;
        *(uint4*)(Bdst)      = PB0;
        *(uint4*)(Bdst + 8)  = PB1;
        *(uint4*)(Bdst + 16) = PB2;
        *(uint4*)(Bdst + 24) = PB3;
        __syncthreads();

        const int kn = k0 + BK;
        if (kn < HDIM) {
            if (arow >= 0) {
                PA0 = *(const uint4*)(ap + kn);
                PA1 = *(const uint4*)(ap + kn + 8);
                PA2 = *(const uint4*)(ap + kn + 16);
                PA3 = *(const uint4*)(ap + kn + 24);
            }
            PB0 = *(const uint4*)(bsrc + kn);
            PB1 = *(const uint4*)(bsrc + kn + 8);
            PB2 = *(const uint4*)(bsrc + kn + 16);
            PB3 = *(const uint4*)(bsrc + kn + 24);
        }

#pragma unroll
        for (int ks = 0; ks < 2; ++ks) {
            const int kc = ks * 32 + quad * 8;
            bf16x8 af[4], bgf[2], buf_[2];
#pragma unroll
            for (int i = 0; i < 4; ++i)
                af[i] = *(const bf16x8*)&As[wm + i * 16 + l16][kc];
#pragma unroll
            for (int j = 0; j < 2; ++j) {
                bgf[j]  = *(const bf16x8*)&Bg[wn + j * 16 + l16][kc];
                buf_[j] = *(const bf16x8*)&Bu[wn + j * 16 + l16][kc];
            }
#pragma unroll
            for (int i = 0; i < 4; ++i)
#pragma unroll
                for (int j = 0; j < 2; ++j) {
                    accg[i][j] = __builtin_amdgcn_mfma_f32_16x16x32_bf16(
                        af[i], bgf[j], accg[i][j], 0, 0, 0);
                    accu[i][j] = __builtin_amdgcn_mfma_f32_16x16x32_bf16(
                        af[i], buf_[j], accu[i][j], 0, 0, 0);
                }
        }
    }

    // epilogue: silu(g)*u -> bf16 act
#pragma unroll
    for (int j = 0; j < 2; ++j) {
        const int nl = n0 + wn + j * 16 + l16;
        const float gbv = gbp[nl];
        const float ubv = ubp[nl];
#pragma unroll
        for (int i = 0; i < 4; ++i) {
#pragma unroll
            for (int ii = 0; ii < 4; ++ii) {
                const int ml = wm + i * 16 + quad * 4 + ii;
                const int orow = or_lds[ml];
                if (orow >= 0) {
                    const float g = accg[i][j][ii] + gbv;
                    const float uu = accu[i][j][ii] + ubv;
                    act[(size_t)orow * IDIM + nl] =
                        f2bf(g * uu / (1.0f + __expf(-g)));
                }
            }
        }
    }
}

// ------------------------------------------------------- down-proj GEMM ----
// Split-K=2, NON-ATOMIC: slice sk writes plain stores into y2 + sk*(2T*H).
// 256 threads / 4 waves; BK=64 (11 k-steps per slice).
__global__ __launch_bounds__(256) void down_kernel(
    const unsigned short* __restrict__ act,   // [2T, IDIM] bf16
    const unsigned short* __restrict__ dwt,   // [E][H][I] bf16
    const float* __restrict__ db,
    const int* __restrict__ counts,
    const float* __restrict__ wgt_list,
    const int* __restrict__ row_list,
    float* __restrict__ y2)                   // [2][2T, HDIM] fp32
{
    const int flat = blockIdx.x;
    const int xcd  = flat & 7;
    const int q    = flat >> 3;
    const int mt   = q & 15;
    const int slot = q >> 4;
    const int P    = slot * 8 + xcd;   // 0..255 = (sk, e, nt)
    const int sk   = P & 1;
    const int en   = P >> 1;
    const int e    = en >> 4;
    const int nt   = en & 15;
    const int n_e  = counts[e];
    const int m0   = mt * BM;
    if (m0 >= n_e) return;
    const int n0 = nt * BN;
    const int ks = sk * DK_HALF;
    float* y2s = y2 + (size_t)sk * 2 * T_TOK * HDIM;

    const unsigned short* dwp = dwt + (size_t)e * HDIM * IDIM;
    const float* dbp = db + (size_t)e * HDIM;

    __shared__ unsigned short As[BM][KPAD];   // 18 KB
    __shared__ unsigned short Bs[BN][KPAD];   //  9 KB
    __shared__ int   r_lds[BM];
    __shared__ float w_lds[BM];

    const int tid = threadIdx.x;
    const int base = e * T_TOK;
    if (tid < BM) {
        const int m = m0 + tid;
        int r = -1; float w = 0.0f;
        if (m < n_e) { r = row_list[base + m]; w = wgt_list[base + m]; }
        r_lds[tid] = r; w_lds[tid] = w;
    }
    __syncthreads();

    const int ar = tid >> 1;
    const int ac = (tid & 1) * 32;
    const int arow = r_lds[ar];
    const unsigned short* ap =
        act + (size_t)(arow < 0 ? 0 : arow) * IDIM + ks + ac;
    unsigned short* Adst = &As[0][0] + ar * KPAD + ac;
    const int brow = tid >> 2;
    const int bch  = (tid & 3) * 16;
    const unsigned short* bsrc = dwp + (size_t)(n0 + brow) * IDIM + ks + bch;
    unsigned short* Bdst = &Bs[0][0] + brow * KPAD + bch;

    const int wv = tid >> 6, lane = tid & 63;
    const int wm = (wv & 1) * 64, wn = (wv >> 1) * 32;
    const int l16 = lane & 15, quad = lane >> 4;

    f32x4 acc[4][2];
    const f32x4 zero = {0.0f, 0.0f, 0.0f, 0.0f};
#pragma unroll
    for (int i = 0; i < 4; ++i)
#pragma unroll
        for (int j = 0; j < 2; ++j) acc[i][j] = zero;

    uint4 PA0 = {0,0,0,0}, PA1 = {0,0,0,0}, PA2 = {0,0,0,0}, PA3 = {0,0,0,0};
    uint4 PB0, PB1;
    if (arow >= 0) {
        PA0 = *(const uint4*)(ap);
        PA1 = *(const uint4*)(ap + 8);
        PA2 = *(const uint4*)(ap + 16);
        PA3 = *(const uint4*)(ap + 24);
    }
    PB0 = *(const uint4*)(bsrc);
    PB1 = *(const uint4*)(bsrc + 8);

    for (int k0 = 0; k0 < DK_HALF; k0 += BK) {
        __syncthreads();
        *(uint4*)(Adst)      = PA0;
        *(uint4*)(Adst + 8)  = PA1;
        *(uint4*)(Adst + 16) = PA2;
        *(uint4*)(Adst + 24) = PA3;
        *(uint4*)(Bdst)      = PB0;
        *(uint4*)(Bdst + 8)  = PB1;
        __syncthreads();

        const int kn = k0 + BK;
        if (kn < DK_HALF) {
            if (arow >= 0) {
                PA0 = *(const uint4*)(ap + kn);
                PA1 = *(const uint4*)(ap + kn + 8);
                PA2 = *(const uint4*)(ap + kn + 16);
                PA3 = *(const uint4*)(ap + kn + 24);
            }
            PB0 = *(const uint4*)(bsrc + kn);
            PB1 = *(const uint4*)(bsrc + kn + 8);
        }

#pragma unroll
        for (int ks2 = 0; ks2 < 2; ++ks2) {
            const int kc = ks2 * 32 + quad * 8;
            bf16x8 af[4], bfr[2];
#pragma unroll
            for (int i = 0; i < 4; ++i)
                af[i] = *(const bf16x8*)&As[wm + i * 16 + l16][kc];
#pragma unroll
            for (int j = 0; j < 2; ++j)
                bfr[j] = *(const bf16x8*)&Bs[wn + j * 16 + l16][kc];
#pragma unroll
            for (int i = 0; i < 4; ++i)
#pragma unroll
                for (int j = 0; j < 2; ++j)
                    acc[i][j] = __builtin_amdgcn_mfma_f32_16x16x32_bf16(
                        af[i], bfr[j], acc[i][j], 0, 0, 0);
        }
    }

#pragma unroll
    for (int j = 0; j < 2; ++j) {
        const int nl = n0 + wn + j * 16 + l16;
        const float bv = (sk == 0) ? dbp[nl] : 0.0f;
#pragma unroll
        for (int i = 0; i < 4; ++i) {
#pragma unroll
            for (int ii = 0; ii < 4; ++ii) {
                const int ml = wm + i * 16 + quad * 4 + ii;
                const int rr = r_lds[ml];
                if (rr >= 0)
                    y2s[(size_t)rr * HDIM + nl] = w_lds[ml] * (acc[i][j][ii] + bv);
            }
        }
    }
}

// --------------------------------------------------------------- combine ----
__global__ __launch_bounds__(256) void combine_kernel(
    const float* __restrict__ y2, float* __restrict__ out)
{
    const int idx = (blockIdx.x * 256 + threadIdx.x) * 4;   // < T*H
    const int t = idx >> 10;           // HDIM == 1024
    const int h = idx & 1023;
    const float* y2b = y2 + (size_t)2 * T_TOK * HDIM;
    const float4 a0 = *(const float4*)(y2  + ((size_t)2 * t) * HDIM + h);
    const float4 a1 = *(const float4*)(y2  + ((size_t)2 * t + 1) * HDIM + h);
    const float4 b0 = *(const float4*)(y2b + ((size_t)2 * t) * HDIM + h);
    const float4 b1 = *(const float4*)(y2b + ((size_t)2 * t + 1) * HDIM + h);
    float4 o;
    o.x = a0.x + a1.x + b0.x + b1.x;
    o.y = a0.y + a1.y + b0.y + b1.y;
    o.z = a0.z + a1.z + b0.z + b1.z;
    o.w = a0.w + a1.w + b0.w + b1.w;
    *(float4*)(out + idx) = o;
}

// ---------------------------------------------------------------- launch ----
extern "C" void kernel_launch(void* const* d_in, const int* in_sizes, int n_in,
                              void* d_out, int out_size, void* d_ws, size_t ws_size,
                              hipStream_t stream)
{
    const float* x      = (const float*)d_in[0];
    const float* rw     = (const float*)d_in[1];
    const float* gate_w = (const float*)d_in[2];
    const float* up_w   = (const float*)d_in[3];
    const float* down_w = (const float*)d_in[4];
    const float* gate_b = (const float*)d_in[5];
    const float* up_b   = (const float*)d_in[6];
    const float* down_b = (const float*)d_in[7];
    float* out = (float*)d_out;

    // workspace layout (~85 MB; y2[2 slices, 32 MB] aliases gwt+uwt,
    // which are dead after gateup)
    char* ws = (char*)d_ws;
    size_t off = 0;
    int*   counts   = (int*)(ws + off);  off += 256;
    int*   tok_list = (int*)(ws + off);  off += 65536;
    float* wgt_list = (float*)(ws + off); off += 65536;
    int*   row_list = (int*)(ws + off);  off += 65536;
    int*   sel      = (int*)(ws + off);  off += T_TOK * 4;
    float* w1arr    = (float*)(ws + off); off += T_TOK * 4;
    unsigned short* x_bf = (unsigned short*)(ws + off); off += (size_t)T_TOK * HDIM * 2;       // 4 MB
    unsigned short* act  = (unsigned short*)(ws + off); off += (size_t)2 * T_TOK * IDIM * 2;   // 11.5 MB
    unsigned short* dwt  = (unsigned short*)(ws + off); off += (size_t)NEXP * IDIM * HDIM * 2; // 23 MB
    unsigned short* gwt  = (unsigned short*)(ws + off); off += (size_t)NEXP * IDIM * HDIM * 2; // 23 MB
    unsigned short* uwt  = (unsigned short*)(ws + off);                                        // 23 MB
    float* y2 = (float*)gwt;   // 2 x 16 MB slices, reused after gateup

    wtrans_all_kernel<<<dim3(176, 1, 24), 256, 0, stream>>>(
        gate_w, up_w, down_w, gwt, uwt, dwt);

    router_compute_kernel<<<T_TOK / 4, 256, 0, stream>>>(x, rw, sel, w1arr, x_bf);

    router_scatter_kernel<<<1, 1024, 0, stream>>>(
        sel, w1arr, counts, tok_list, wgt_list, row_list);

    gateup_kernel<<<8 * GU_NT * MT_SLOTS, 256, 0, stream>>>(
        x_bf, gwt, uwt, gate_b, up_b, counts, tok_list, row_list, act);

    down_kernel<<<2 * 8 * DN_NT * MT_SLOTS, 256, 0, stream>>>(
        act, dwt, down_b, counts, wgt_list, row_list, y2);

    combine_kernel<<<(T_TOK * HDIM / 4) / 256, 256, 0, stream>>>(y2, out);
}